// Round 11
// baseline (63.967 us; speedup 1.0000x reference)
//
#include <hip/hip_runtime.h>
#include <math.h>

#define TOKENS 16384
#define HID    2048
#define KC     64
#define NCH    32
#define TPB    32          // tokens per block

typedef float f4 __attribute__((ext_vector_type(4)));
typedef short s8v __attribute__((ext_vector_type(8)));

// ws byte layout
#define WS_W1    0                      // ushort[64*2048] bf16 plane1 (256KB)
#define WS_W2    262144                 // ushort[64*2048] bf16 plane2 (256KB)
#define WS_BP    524288                 // float[512*128] (256KB)
#define WS_G2    786432                 // float[64*128] (32KB)

__device__ __forceinline__ unsigned short bf16rne(float x) {
  unsigned u = __float_as_uint(x);
  return (unsigned short)((u + 0x7FFFu + ((u >> 16) & 1u)) >> 16);
}

__device__ __forceinline__ void gl16(const void* g, const void* l) {
  __builtin_amdgcn_global_load_lds(
      (const __attribute__((address_space(1))) void*)g,
      (__attribute__((address_space(3))) void*)l, 16, 0, 0);
}

#define BARK(N) { asm volatile("s_waitcnt vmcnt(" #N ") lgkmcnt(0)" ::: "memory"); \
  __builtin_amdgcn_sched_barrier(0); __builtin_amdgcn_s_barrier(); \
  __builtin_amdgcn_sched_barrier(0); }

// fp32 weights -> two bf16 planes (w ~= w1 + w2, residual ~2^-18)
__global__ __launch_bounds__(256) void k_pack(const float* __restrict__ gw,
                                              unsigned short* __restrict__ w1,
                                              unsigned short* __restrict__ w2) {
  int gid = blockIdx.x * 256 + threadIdx.x;   // 16384 threads * 8 els
  int m = gid * 8;
  f4 a = *(const f4*)(gw + m);
  f4 b = *(const f4*)(gw + m + 4);
  float av[8] = {a.x, a.y, a.z, a.w, b.x, b.y, b.z, b.w};
  unsigned short p1[8], p2[8];
  #pragma unroll
  for (int i = 0; i < 8; ++i) {
    unsigned short h = bf16rne(av[i]);
    p1[i] = h;
    float r = av[i] - __uint_as_float((unsigned)h << 16);
    p2[i] = bf16rne(r);
  }
  *(s8v*)(w1 + m) = *(s8v*)p1;
  *(s8v*)(w2 + m) = *(s8v*)p2;
}

__global__ __launch_bounds__(256, 2) void k_main(const float* __restrict__ hid,
                                                 const unsigned short* __restrict__ w1,
                                                 const unsigned short* __restrict__ w2,
                                                 float* __restrict__ out,
                                                 float* __restrict__ bp) {
  // 3 buffers * 24576B: A fp32 [32 tok][256B] + w1 [64 e][128B] + w2 [64 e][128B]
  // XOR swizzle confined to 64B lines (granule ^ (row&3)) -> coalesced source quads
  __shared__ __align__(16) char lds[73728];
  const int tid = threadIdx.x, wave = tid >> 6, lane = tid & 63;
  const int th = wave >> 1, eh = wave & 1;       // token-half, expert-half
  const int l15 = lane & 15, ks = lane >> 4;
  const int tok0 = blockIdx.x * TPB;

  // ---- staging sources (64B-line-local granule permutation; LDS dest linear) ----
  const char* hb = (const char*)hid;
  size_t asrc[2];
  #pragma unroll
  for (int j = 0; j < 2; ++j) {
    int row = j * 16 + (tid >> 4);
    asrc[j] = (size_t)(tok0 + row) * 8192 + (size_t)(((tid & 15) ^ (row & 3)) << 4);
  }
  const char* w1b = (const char*)w1;
  const char* w2b = (const char*)w2;
  size_t bsrc[2];
  #pragma unroll
  for (int j = 0; j < 2; ++j) {
    int e = j * 32 + (tid >> 3);
    bsrc[j] = (size_t)e * 4096 + (size_t)(((tid & 7) ^ (e & 3)) << 4);
  }

  f4 acc[2] = {{0.f,0.f,0.f,0.f},{0.f,0.f,0.f,0.f}};
  const int arow = th * 16 + l15, asw = arow & 3;
  const int be[2] = {eh * 32 + l15, eh * 32 + 16 + l15};

  auto stage = [&](int c, int bufb) {
    #pragma unroll
    for (int j = 0; j < 2; ++j)
      gl16(hb + asrc[j] + (size_t)c * 256, lds + bufb + j * 4096 + wave * 1024);
    #pragma unroll
    for (int j = 0; j < 2; ++j)
      gl16(w1b + bsrc[j] + (size_t)c * 128, lds + bufb + 8192 + j * 4096 + wave * 1024);
    #pragma unroll
    for (int j = 0; j < 2; ++j)
      gl16(w2b + bsrc[j] + (size_t)c * 128, lds + bufb + 16384 + j * 4096 + wave * 1024);
  };

  auto compute = [&](int bufb) {
    #pragma unroll
    for (int s = 0; s < 2; ++s) {
      int g0 = (s * 8 + ks * 2) ^ asw;
      int g1 = (s * 8 + ks * 2 + 1) ^ asw;
      f4 a0 = *(const f4*)(lds + bufb + arow * 256 + g0 * 16);
      f4 a1 = *(const f4*)(lds + bufb + arow * 256 + g1 * 16);
      float av[8] = {a0.x, a0.y, a0.z, a0.w, a1.x, a1.y, a1.z, a1.w};
      unsigned short p1[8], p2[8];
      #pragma unroll
      for (int i = 0; i < 8; ++i) {
        unsigned short h = bf16rne(av[i]);
        p1[i] = h;
        float r = av[i] - __uint_as_float((unsigned)h << 16);
        p2[i] = bf16rne(r);
      }
      s8v af1 = *(s8v*)p1;
      s8v af2 = *(s8v*)p2;
      #pragma unroll
      for (int nj = 0; nj < 2; ++nj) {
        int g = (s * 4 + ks) ^ (be[nj] & 3);
        s8v bw1 = *(const s8v*)(lds + bufb + 8192  + be[nj] * 128 + g * 16);
        s8v bw2 = *(const s8v*)(lds + bufb + 16384 + be[nj] * 128 + g * 16);
        acc[nj] = __builtin_amdgcn_mfma_f32_16x16x32_bf16(af1, bw1, acc[nj], 0, 0, 0);
        acc[nj] = __builtin_amdgcn_mfma_f32_16x16x32_bf16(af1, bw2, acc[nj], 0, 0, 0);
        acc[nj] = __builtin_amdgcn_mfma_f32_16x16x32_bf16(af2, bw1, acc[nj], 0, 0, 0);
      }
    }
  };

  stage(0, 0);
  stage(1, 24576);
  BARK(6);

  for (int c = 0; c < NCH; ++c) {
    const int bufb = (c % 3) * 24576;
    if (c + 2 < NCH) stage(c + 2, ((c + 2) % 3) * 24576);
    compute(bufb);
    if (c + 2 < NCH) { BARK(6); } else { BARK(0); }
  }

  // ---- epilogue: park logits [32 tok][68] fp32 ----
  float* lf = (float*)lds;
  #pragma unroll
  for (int nj = 0; nj < 2; ++nj)
    #pragma unroll
    for (int r = 0; r < 4; ++r)
      lf[(th * 16 + ks * 4 + r) * 68 + eh * 32 + nj * 16 + l15] = acc[nj][r];
  __syncthreads();

  float spacc = 0.f, cntacc = 0.f;
  for (int it = 0; it < 8; ++it) {
    const int tl = wave * 8 + it;
    float lg = lf[tl * 68 + lane];
    float m1 = lg;
    #pragma unroll
    for (int d = 1; d < 64; d <<= 1) m1 = fmaxf(m1, __shfl_xor(m1, d));
    int c0 = (lg == m1) ? lane : 64;
    #pragma unroll
    for (int d = 1; d < 64; d <<= 1) c0 = min(c0, __shfl_xor(c0, d));
    float lx1 = (lane == c0) ? -INFINITY : lg;
    float m2 = lx1;
    #pragma unroll
    for (int d = 1; d < 64; d <<= 1) m2 = fmaxf(m2, __shfl_xor(m2, d));
    int c1 = (lx1 == m2) ? lane : 64;
    #pragma unroll
    for (int d = 1; d < 64; d <<= 1) c1 = min(c1, __shfl_xor(c1, d));

    float p = __expf(lg - m1);
    float Z = p;
    #pragma unroll
    for (int d = 1; d < 64; d <<= 1) Z += __shfl_xor(Z, d);
    spacc = fmaf(p, 1.f / Z, spacc);
    cntacc += ((lane == c0) ? 1.f : 0.f) + ((lane == c1) ? 1.f : 0.f);

    float gr = __expf(m2 - m1);
    float r0 = 1.f / (1.f + gr);
    if (lane == 0) {
      int t = tok0 + tl;
      out[(size_t)t * 2]     = r0;
      out[(size_t)t * 2 + 1] = gr * r0;
      out[(size_t)TOKENS * 2 + t * 2]     = (float)c0;
      out[(size_t)TOKENS * 2 + t * 2 + 1] = (float)c1;
    }
  }

  float* red = lf + 2304;
  red[wave * 128 + lane]      = spacc;
  red[wave * 128 + 64 + lane] = cntacc;
  __syncthreads();
  if (tid < 128) {
    float s = red[tid] + red[128 + tid] + red[256 + tid] + red[384 + tid];
    bp[(size_t)blockIdx.x * 128 + tid] = s;
  }
}

__global__ __launch_bounds__(128) void k_loss1(const float* __restrict__ bp,
                                               float* __restrict__ g2) {
  float s = 0.f;
  #pragma unroll 4
  for (int j = 0; j < 8; ++j)
    s += bp[(size_t)(blockIdx.x * 8 + j) * 128 + threadIdx.x];
  g2[(size_t)blockIdx.x * 128 + threadIdx.x] = s;
}

__global__ __launch_bounds__(128) void k_loss2(const float* __restrict__ g2,
                                               float* __restrict__ out) {
  const int tid = threadIdx.x;
  float s = 0.f;
  #pragma unroll 8
  for (int j = 0; j < 64; ++j) s += g2[(size_t)j * 128 + tid];
  __shared__ float red[128];
  red[tid] = s;
  __syncthreads();
  if (tid < 64) {
    float v = red[tid] * red[64 + tid];   // sumprob_e * count_e
    #pragma unroll
    for (int d = 1; d < 64; d <<= 1) v += __shfl_xor(v, d);
    if (tid == 0)
      out[(size_t)TOKENS * 4] = 0.01f * 64.f * v / (16384.f * 16384.f);
  }
}

extern "C" void kernel_launch(void* const* d_in, const int* in_sizes, int n_in,
                              void* d_out, int out_size, void* d_ws, size_t ws_size,
                              hipStream_t stream) {
  (void)in_sizes; (void)n_in; (void)out_size; (void)ws_size;
  const float* hid = (const float*)d_in[0];
  const float* gw  = (const float*)d_in[1];
  float* out = (float*)d_out;
  char* ws = (char*)d_ws;
  unsigned short* w1 = (unsigned short*)(ws + WS_W1);
  unsigned short* w2 = (unsigned short*)(ws + WS_W2);
  float* bp    = (float*)(ws + WS_BP);
  float* g2    = (float*)(ws + WS_G2);

  k_pack <<<64, 256, 0, stream>>>(gw, w1, w2);
  k_main <<<512, 256, 0, stream>>>(hid, w1, w2, out, bp);
  k_loss1<<<64, 128, 0, stream>>>(bp, g2);
  k_loss2<<<1, 128, 0, stream>>>(g2, out);
}

// Round 12
// 54.226 us; speedup vs baseline: 1.1796x; 1.1796x over previous
//
#include <hip/hip_runtime.h>
#include <math.h>

#define TOKENS 16384
#define HID    2048
#define NCH    32
#define TPB    64          // tokens per block

typedef float f4 __attribute__((ext_vector_type(4)));
typedef short s8v __attribute__((ext_vector_type(8)));

// ws byte layout
#define WS_W1    0                      // ushort[64*2048] bf16 plane1 (256KB)
#define WS_W2    262144                 // ushort[64*2048] bf16 plane2 (256KB)
#define WS_BP    524288                 // float[256*128] (128KB)
#define WS_G2    786432                 // float[32*128] (16KB)

__device__ __forceinline__ unsigned short bf16rne(float x) {
  unsigned u = __float_as_uint(x);
  return (unsigned short)((u + 0x7FFFu + ((u >> 16) & 1u)) >> 16);
}

__device__ __forceinline__ void gl16(const void* g, const void* l) {
  __builtin_amdgcn_global_load_lds(
      (const __attribute__((address_space(1))) void*)g,
      (__attribute__((address_space(3))) void*)l, 16, 0, 0);
}

#define BARK(N) { asm volatile("s_waitcnt vmcnt(" #N ") lgkmcnt(0)" ::: "memory"); \
  __builtin_amdgcn_sched_barrier(0); __builtin_amdgcn_s_barrier(); \
  __builtin_amdgcn_sched_barrier(0); }

// fp32 weights -> two bf16 planes (w ~= w1 + w2, residual ~2^-18)
__global__ __launch_bounds__(256) void k_pack(const float* __restrict__ gw,
                                              unsigned short* __restrict__ w1,
                                              unsigned short* __restrict__ w2) {
  int gid = blockIdx.x * 256 + threadIdx.x;   // 16384 threads * 8 els
  int m = gid * 8;
  f4 a = *(const f4*)(gw + m);
  f4 b = *(const f4*)(gw + m + 4);
  float av[8] = {a.x, a.y, a.z, a.w, b.x, b.y, b.z, b.w};
  unsigned short p1[8], p2[8];
  #pragma unroll
  for (int i = 0; i < 8; ++i) {
    unsigned short h = bf16rne(av[i]);
    p1[i] = h;
    float r = av[i] - __uint_as_float((unsigned)h << 16);
    p2[i] = bf16rne(r);
  }
  *(s8v*)(w1 + m) = *(s8v*)p1;
  *(s8v*)(w2 + m) = *(s8v*)p2;
}

__global__ __launch_bounds__(512, 1) void k_main(const float* __restrict__ hid,
                                                 const unsigned short* __restrict__ w1,
                                                 const unsigned short* __restrict__ w2,
                                                 float* __restrict__ out,
                                                 float* __restrict__ bp) {
  // 4 buffers * 32768B: A fp32 [64 tok][256B] (16KB) + w1 [64 e][128B] (8KB) + w2 (8KB)
  __shared__ __align__(16) char lds[131072];
  const int tid = threadIdx.x, wave = tid >> 6, lane = tid & 63;
  const int th = wave >> 1, eh = wave & 1;       // 4 token-strips x 2 expert-halves
  const int l15 = lane & 15, ks = lane >> 4;
  const int tok0 = blockIdx.x * TPB;

  // ---- staging sources (64B-line-local granule permutation; LDS dest linear) ----
  const char* hb = (const char*)hid;
  size_t asrc[2]; int adst[2];
  #pragma unroll
  for (int j = 0; j < 2; ++j) {
    int u = j * 512 + tid;
    int row = u >> 4, g = u & 15;
    asrc[j] = (size_t)(tok0 + row) * 8192 + (size_t)((g ^ (row & 3)) << 4);
    adst[j] = u * 16;
  }
  const char* w1b = (const char*)w1;
  const char* w2b = (const char*)w2;
  const int eB = tid >> 3, gB = tid & 7;
  const size_t bsrc = (size_t)eB * 4096 + (size_t)((gB ^ (eB & 3)) << 4);

  f4 acc[2] = {{0.f,0.f,0.f,0.f},{0.f,0.f,0.f,0.f}};
  const int arow = th * 16 + l15, asw = arow & 3;
  const int be[2] = {eh * 32 + l15, eh * 32 + 16 + l15};

  auto stage = [&](int c, int bufb) {
    #pragma unroll
    for (int j = 0; j < 2; ++j)
      gl16(hb + asrc[j] + (size_t)c * 256, lds + bufb + adst[j]);
    gl16(w1b + bsrc + (size_t)c * 128, lds + bufb + 16384 + tid * 16);
    gl16(w2b + bsrc + (size_t)c * 128, lds + bufb + 24576 + tid * 16);
  };

  auto compute = [&](int bufb) {
    #pragma unroll
    for (int s = 0; s < 2; ++s) {
      int g0 = (s * 8 + ks * 2) ^ asw;
      int g1 = (s * 8 + ks * 2 + 1) ^ asw;
      f4 a0 = *(const f4*)(lds + bufb + arow * 256 + g0 * 16);
      f4 a1 = *(const f4*)(lds + bufb + arow * 256 + g1 * 16);
      float av[8] = {a0.x, a0.y, a0.z, a0.w, a1.x, a1.y, a1.z, a1.w};
      unsigned short p1[8], p2[8];
      #pragma unroll
      for (int i = 0; i < 8; ++i) {
        unsigned short h = bf16rne(av[i]);
        p1[i] = h;
        float r = av[i] - __uint_as_float((unsigned)h << 16);
        p2[i] = bf16rne(r);
      }
      s8v af1 = *(s8v*)p1;
      s8v af2 = *(s8v*)p2;
      #pragma unroll
      for (int nj = 0; nj < 2; ++nj) {
        int g = (s * 4 + ks) ^ (be[nj] & 3);
        s8v bw1 = *(const s8v*)(lds + bufb + 16384 + be[nj] * 128 + g * 16);
        s8v bw2 = *(const s8v*)(lds + bufb + 24576 + be[nj] * 128 + g * 16);
        acc[nj] = __builtin_amdgcn_mfma_f32_16x16x32_bf16(af1, bw1, acc[nj], 0, 0, 0);
        acc[nj] = __builtin_amdgcn_mfma_f32_16x16x32_bf16(af1, bw2, acc[nj], 0, 0, 0);
        acc[nj] = __builtin_amdgcn_mfma_f32_16x16x32_bf16(af2, bw1, acc[nj], 0, 0, 0);
      }
    }
  };

  stage(0, 0);
  stage(1, 32768);
  stage(2, 65536);
  BARK(8);

  for (int c = 0; c < NCH; ++c) {
    const int bufb = (c & 3) * 32768;
    if (c + 3 < NCH) stage(c + 3, ((c + 3) & 3) * 32768);
    compute(bufb);
    if (c + 3 < NCH)      { BARK(8); }
    else if (c + 2 < NCH) { BARK(4); }
    else                  { BARK(0); }
  }

  // ---- epilogue: park logits [64 tok][68] fp32 ----
  float* lf = (float*)lds;
  #pragma unroll
  for (int nj = 0; nj < 2; ++nj)
    #pragma unroll
    for (int r = 0; r < 4; ++r)
      lf[(th * 16 + ks * 4 + r) * 68 + eh * 32 + nj * 16 + l15] = acc[nj][r];
  __syncthreads();

  float spacc = 0.f, cntacc = 0.f;
  for (int it = 0; it < 8; ++it) {
    const int tl = wave * 8 + it;
    float lg = lf[tl * 68 + lane];
    float m1 = lg;
    #pragma unroll
    for (int d = 1; d < 64; d <<= 1) m1 = fmaxf(m1, __shfl_xor(m1, d));
    int c0 = (lg == m1) ? lane : 64;
    #pragma unroll
    for (int d = 1; d < 64; d <<= 1) c0 = min(c0, __shfl_xor(c0, d));
    float lx1 = (lane == c0) ? -INFINITY : lg;
    float m2 = lx1;
    #pragma unroll
    for (int d = 1; d < 64; d <<= 1) m2 = fmaxf(m2, __shfl_xor(m2, d));
    int c1 = (lx1 == m2) ? lane : 64;
    #pragma unroll
    for (int d = 1; d < 64; d <<= 1) c1 = min(c1, __shfl_xor(c1, d));

    float p = __expf(lg - m1);
    float Z = p;
    #pragma unroll
    for (int d = 1; d < 64; d <<= 1) Z += __shfl_xor(Z, d);
    spacc = fmaf(p, 1.f / Z, spacc);
    cntacc += ((lane == c0) ? 1.f : 0.f) + ((lane == c1) ? 1.f : 0.f);

    float gr = __expf(m2 - m1);
    float r0 = 1.f / (1.f + gr);
    if (lane == 0) {
      int t = tok0 + tl;
      out[(size_t)t * 2]     = r0;
      out[(size_t)t * 2 + 1] = gr * r0;
      out[(size_t)TOKENS * 2 + t * 2]     = (float)c0;
      out[(size_t)TOKENS * 2 + t * 2 + 1] = (float)c1;
    }
  }

  float* red = lf + 4352;
  red[wave * 128 + lane]      = spacc;
  red[wave * 128 + 64 + lane] = cntacc;
  __syncthreads();
  if (tid < 128) {
    float s = 0.f;
    #pragma unroll
    for (int w = 0; w < 8; ++w) s += red[w * 128 + tid];
    bp[(size_t)blockIdx.x * 128 + tid] = s;
  }
}

__global__ __launch_bounds__(128) void k_loss1(const float* __restrict__ bp,
                                               float* __restrict__ g2) {
  float s = 0.f;
  #pragma unroll 4
  for (int j = 0; j < 8; ++j)
    s += bp[(size_t)(blockIdx.x * 8 + j) * 128 + threadIdx.x];
  g2[(size_t)blockIdx.x * 128 + threadIdx.x] = s;
}

__global__ __launch_bounds__(128) void k_loss2(const float* __restrict__ g2,
                                               float* __restrict__ out) {
  const int tid = threadIdx.x;
  float s = 0.f;
  #pragma unroll 8
  for (int j = 0; j < 32; ++j) s += g2[(size_t)j * 128 + tid];
  __shared__ float red[128];
  red[tid] = s;
  __syncthreads();
  if (tid < 64) {
    float v = red[tid] * red[64 + tid];   // sumprob_e * count_e
    #pragma unroll
    for (int d = 1; d < 64; d <<= 1) v += __shfl_xor(v, d);
    if (tid == 0)
      out[(size_t)TOKENS * 4] = 0.01f * 64.f * v / (16384.f * 16384.f);
  }
}

extern "C" void kernel_launch(void* const* d_in, const int* in_sizes, int n_in,
                              void* d_out, int out_size, void* d_ws, size_t ws_size,
                              hipStream_t stream) {
  (void)in_sizes; (void)n_in; (void)out_size; (void)ws_size;
  const float* hid = (const float*)d_in[0];
  const float* gw  = (const float*)d_in[1];
  float* out = (float*)d_out;
  char* ws = (char*)d_ws;
  unsigned short* w1 = (unsigned short*)(ws + WS_W1);
  unsigned short* w2 = (unsigned short*)(ws + WS_W2);
  float* bp    = (float*)(ws + WS_BP);
  float* g2    = (float*)(ws + WS_G2);

  k_pack <<<64, 256, 0, stream>>>(gw, w1, w2);
  k_main <<<256, 512, 0, stream>>>(hid, w1, w2, out, bp);
  k_loss1<<<32, 128, 0, stream>>>(bp, g2);
  k_loss2<<<1, 128, 0, stream>>>(g2, out);
}